// Round 1
// baseline (296.568 us; speedup 1.0000x reference)
//
#include <hip/hip_runtime.h>

// MoE: M=4096, K=1024, E=8, N=1024, TOPK=2
// out[m] = sum_t topk_w[m,t] * ( silu(hs[m]@w1[e][:, :N]) * (hs[m]@w1[e][:, N:]) ) @ w2[e]
//   with e = topk_ids[m,t]

#define M_TOK   4096
#define K_DIM   1024
#define N_DIM   1024
#define E_NUM   8
#define NPAIR   8192            // M_TOK * TOPK
#define BM      128
#define ROWS_CAP 9216           // NPAIR + E_NUM*BM  (worst-case padded rows)
#define NROWBLK 72              // ROWS_CAP / BM

typedef unsigned short u16;
typedef unsigned int   u32;
typedef __attribute__((ext_vector_type(8))) short bf16x8;
typedef __attribute__((ext_vector_type(4))) float f32x4;

#define GPTR(p) ((const __attribute__((address_space(1))) u32*)(const void*)(p))
#define LPTR(p) ((__attribute__((address_space(3))) u32*)(void*)(p))

__device__ __forceinline__ u16 f2bf(float f) {
  union { float f; u32 u; } v; v.f = f;
  u32 r = v.u + 0x7FFFu + ((v.u >> 16) & 1u);   // RNE
  return (u16)(r >> 16);
}
__device__ __forceinline__ float bf2f(u16 u) {
  union { u32 u; float f; } v; v.u = ((u32)u) << 16;
  return v.f;
}

// ---------------- routing: bucket pairs by expert, pad segments to BM ----------
__global__ __launch_bounds__(256) void routing_kernel(
    const int* __restrict__ topk_ids, int* __restrict__ pair_token,
    int* __restrict__ pos_of, int* __restrict__ block_expert) {
  __shared__ int cnt[E_NUM], off[E_NUM], cur[E_NUM], pad[E_NUM];
  int t = threadIdx.x;
  if (t < E_NUM) cnt[t] = 0;
  __syncthreads();
  for (int p = t; p < NPAIR; p += 256) {
    int e = topk_ids[p] & 7;
    atomicAdd(&cnt[e], 1);
  }
  __syncthreads();
  if (t == 0) {
    int run = 0, blk = 0;
    for (int e = 0; e < E_NUM; ++e) {
      off[e] = run;
      int padded = ((cnt[e] + BM - 1) / BM) * BM;
      pad[e] = padded;
      for (int b = 0; b < padded / BM; ++b) block_expert[blk++] = e;
      run += padded;
    }
    for (; blk < NROWBLK; ++blk) block_expert[blk] = -1;
  }
  __syncthreads();
  if (t < E_NUM) cur[t] = off[t];
  __syncthreads();
  // pad rows point at token 0 (computed but never gathered)
  for (int e = 0; e < E_NUM; ++e) {
    int s = off[e] + cnt[e], epos = off[e] + pad[e];
    for (int r = s + t; r < epos; r += 256) pair_token[r] = 0;
  }
  for (int p = t; p < NPAIR; p += 256) {
    int e = topk_ids[p] & 7;
    int pos = atomicAdd(&cur[e], 1);
    pair_token[pos] = p >> 1;     // token id
    pos_of[p] = pos;
  }
}

// ---------------- fp32 -> bf16 flat convert (hidden states) -------------------
__global__ __launch_bounds__(256) void convert_kernel(
    const float* __restrict__ in, u16* __restrict__ out) {
  int i = blockIdx.x * 256 + threadIdx.x;
  float4 v = ((const float4*)in)[i];
  ushort4 o;
  o.x = f2bf(v.x); o.y = f2bf(v.y); o.z = f2bf(v.z); o.w = f2bf(v.w);
  ((ushort4*)out)[i] = o;
}

// ---------------- fp32 (R,Cc) -> bf16 (Cc,R) transpose per matrix -------------
__global__ __launch_bounds__(256) void transpose_convert(
    const float* __restrict__ in, u16* __restrict__ out, int R, int Cc) {
  __shared__ float lds[64][65];
  const float* src = in + (size_t)blockIdx.z * R * Cc;
  u16* dst = out + (size_t)blockIdx.z * R * Cc;
  int r0 = blockIdx.x * 64, c0 = blockIdx.y * 64;
  int t = threadIdx.x;
#pragma unroll
  for (int it = 0; it < 16; ++it) {
    int lin = it * 256 + t;
    int rr = lin >> 6, cc = lin & 63;
    lds[cc][rr] = src[(size_t)(r0 + rr) * Cc + c0 + cc];
  }
  __syncthreads();
#pragma unroll
  for (int it = 0; it < 8; ++it) {
    int lin = it * 512 + t * 2;
    int cc = lin >> 6, rr = lin & 63;
    ushort2 o;
    o.x = f2bf(lds[cc][rr]);
    o.y = f2bf(lds[cc][rr + 1]);
    *(ushort2*)&dst[(size_t)(c0 + cc) * R + r0 + rr] = o;
  }
}

// ---------------- grouped GEMM: C[rows,Ncols] = A[rows,K] @ Bt[Ncols,K]^T -----
// 128x128 tile, BK=64, 4 waves each 64x64 via 4x4 of 16x16x32 bf16 MFMA.
// XOR-swizzled 16B chunks in LDS: position p in a row holds global chunk
// p ^ (row&7) -> ds_read_b128 fragment reads spread across banks.
template <bool GATHER>
__global__ __launch_bounds__(256) void gemm_bt(
    const u16* __restrict__ A, const u16* __restrict__ Bt, u16* __restrict__ C,
    const int* __restrict__ pair_token, const int* __restrict__ block_expert,
    int Ncols) {
  const int e = block_expert[blockIdx.x];
  if (e < 0) return;
  __shared__ __align__(16) u16 As[128 * 64];
  __shared__ __align__(16) u16 Bs[128 * 64];
  const int tid = threadIdx.x;
  const int wave = tid >> 6;
  const int lane = tid & 63;
  const int wm = (wave >> 1) * 64;
  const int wn = (wave & 1) * 64;
  const int srow = wave * 8 + (lane >> 3);   // staging row within 32-row group
  const int schunk = lane & 7;               // 16B chunk position in LDS row

  const u16* aptr[4];
  const u16* bptr[4];
  const u16* Bbase = Bt + (size_t)e * Ncols * K_DIM + (size_t)blockIdx.y * 128 * K_DIM;
#pragma unroll
  for (int is = 0; is < 4; ++is) {
    int rt = is * 32 + srow;                 // row within 128-tile
    int grow = blockIdx.x * 128 + rt;
    int arow = GATHER ? pair_token[grow] : grow;
    int kc = (schunk ^ (rt & 7)) << 3;       // swizzled source chunk (elements)
    aptr[is] = A + (size_t)arow * K_DIM + kc;
    bptr[is] = Bbase + (size_t)rt * K_DIM + kc;
  }
  u16* alds = As + wave * 512;
  u16* blds = Bs + wave * 512;

  f32x4 acc[4][4];
#pragma unroll
  for (int i = 0; i < 4; ++i)
#pragma unroll
    for (int j = 0; j < 4; ++j) acc[i][j] = f32x4{0.f, 0.f, 0.f, 0.f};

  for (int k0 = 0; k0 < K_DIM; k0 += 64) {
#pragma unroll
    for (int is = 0; is < 4; ++is)
      __builtin_amdgcn_global_load_lds(GPTR(aptr[is] + k0), LPTR(alds + is * 2048), 16, 0, 0);
#pragma unroll
    for (int is = 0; is < 4; ++is)
      __builtin_amdgcn_global_load_lds(GPTR(bptr[is] + k0), LPTR(blds + is * 2048), 16, 0, 0);
    __syncthreads();   // compiler drains vmcnt before s_barrier
#pragma unroll
    for (int ks = 0; ks < 2; ++ks) {
      bf16x8 af[4], bfr[4];
      const int cq = ks * 4 + (lane >> 4);   // global 16B-chunk index 0..7
#pragma unroll
      for (int i = 0; i < 4; ++i) {
        int row = wm + i * 16 + (lane & 15);
        af[i] = *(const bf16x8*)&As[row * 64 + ((cq ^ (row & 7)) << 3)];
      }
#pragma unroll
      for (int j = 0; j < 4; ++j) {
        int n = wn + j * 16 + (lane & 15);
        bfr[j] = *(const bf16x8*)&Bs[n * 64 + ((cq ^ (n & 7)) << 3)];
      }
#pragma unroll
      for (int i = 0; i < 4; ++i)
#pragma unroll
        for (int j = 0; j < 4; ++j)
          acc[i][j] = __builtin_amdgcn_mfma_f32_16x16x32_bf16(af[i], bfr[j], acc[i][j], 0, 0, 0);
    }
    __syncthreads();
  }

  // epilogue: C/D layout col=lane&15, row=(lane>>4)*4+reg (m89/m91-verified)
  const size_t rbase = (size_t)blockIdx.x * 128 + wm + ((lane >> 4) * 4);
  const int cbase = blockIdx.y * 128 + wn + (lane & 15);
#pragma unroll
  for (int i = 0; i < 4; ++i)
#pragma unroll
    for (int j = 0; j < 4; ++j)
#pragma unroll
      for (int r = 0; r < 4; ++r)
        C[(rbase + i * 16 + r) * Ncols + cbase + j * 16] = f2bf(acc[i][j][r]);
}

// ---------------- silu(gate) * up ---------------------------------------------
__global__ __launch_bounds__(256) void silu_mul_kernel(
    const u16* __restrict__ gu, u16* __restrict__ h) {
  size_t i = ((size_t)blockIdx.x * 256 + threadIdx.x) * 4;
  size_t row = i >> 10;
  int col = (int)(i & 1023);
  const u16* gp = gu + row * 2048 + col;
  ushort4 g4 = *(const ushort4*)gp;
  ushort4 u4 = *(const ushort4*)(gp + 1024);
  ushort4 r4;
  float g, u;
  g = bf2f(g4.x); u = bf2f(u4.x); r4.x = f2bf(g * u / (1.f + __expf(-g)));
  g = bf2f(g4.y); u = bf2f(u4.y); r4.y = f2bf(g * u / (1.f + __expf(-g)));
  g = bf2f(g4.z); u = bf2f(u4.z); r4.z = f2bf(g * u / (1.f + __expf(-g)));
  g = bf2f(g4.w); u = bf2f(u4.w); r4.w = f2bf(g * u / (1.f + __expf(-g)));
  *(ushort4*)&h[row * 1024 + col] = r4;
}

// ---------------- gather: out[m] = w0*y[pos0] + w1*y[pos1] --------------------
__global__ __launch_bounds__(256) void gather_kernel(
    const u16* __restrict__ y, const float* __restrict__ tw,
    const int* __restrict__ pos_of, float* __restrict__ out) {
  int m = blockIdx.x;
  int k = threadIdx.x * 4;
  int p0 = pos_of[m * 2 + 0], p1 = pos_of[m * 2 + 1];
  float w0 = tw[m * 2 + 0], w1 = tw[m * 2 + 1];
  ushort4 y0 = *(const ushort4*)&y[(size_t)p0 * 1024 + k];
  ushort4 y1 = *(const ushort4*)&y[(size_t)p1 * 1024 + k];
  float4 o;
  o.x = w0 * bf2f(y0.x) + w1 * bf2f(y1.x);
  o.y = w0 * bf2f(y0.y) + w1 * bf2f(y1.y);
  o.z = w0 * bf2f(y0.z) + w1 * bf2f(y1.z);
  o.w = w0 * bf2f(y0.w) + w1 * bf2f(y1.w);
  *(float4*)&out[(size_t)m * 1024 + k] = o;
}

extern "C" void kernel_launch(void* const* d_in, const int* in_sizes, int n_in,
                              void* d_out, int out_size, void* d_ws, size_t ws_size,
                              hipStream_t stream) {
  const float* hs = (const float*)d_in[0];
  const float* w1 = (const float*)d_in[1];
  const float* w2 = (const float*)d_in[2];
  const float* tw = (const float*)d_in[3];
  const int* tids = (const int*)d_in[4];
  float* out = (float*)d_out;

  char* ws = (char*)d_ws;
  u16* hsb = (u16*)(ws);                                 // 8 MB
  u16* w1t = (u16*)(ws + (size_t)(8u << 20));            // 32 MB  (E,2N,K)
  u16* w2t = (u16*)(ws + (size_t)(40u << 20));           // 16 MB  (E,K,N)
  u16* gu  = (u16*)(ws + (size_t)(56u << 20));           // 36 MB  (ROWS_CAP,2N)
  u16* h   = (u16*)(ws + (size_t)(92u << 20));           // 18 MB  (ROWS_CAP,N)
  u16* y   = (u16*)(ws + (size_t)(110u << 20));          // 18 MB  (ROWS_CAP,K)
  int* pair_token   = (int*)(ws + (size_t)(128u << 20));
  int* pos_of       = (int*)(ws + (size_t)(128u << 20) + 64 * 1024);
  int* block_expert = (int*)(ws + (size_t)(128u << 20) + 128 * 1024);

  routing_kernel<<<1, 256, 0, stream>>>(tids, pair_token, pos_of, block_expert);
  convert_kernel<<<4096, 256, 0, stream>>>(hs, hsb);
  transpose_convert<<<dim3(16, 32, E_NUM), 256, 0, stream>>>(w1, w1t, 1024, 2048);
  transpose_convert<<<dim3(16, 16, E_NUM), 256, 0, stream>>>(w2, w2t, 1024, 1024);
  gemm_bt<true><<<dim3(NROWBLK, 16), 256, 0, stream>>>(hsb, w1t, gu, pair_token, block_expert, 2048);
  silu_mul_kernel<<<9216, 256, 0, stream>>>(gu, h);
  gemm_bt<false><<<dim3(NROWBLK, 8), 256, 0, stream>>>(h, w2t, y, pair_token, block_expert, 1024);
  gather_kernel<<<4096, 256, 0, stream>>>(y, tw, pos_of, out);
}